// Round 1
// baseline (43507.285 us; speedup 1.0000x reference)
//
#include <hip/hip_runtime.h>
#include <math.h>

// Problem constants (fixed shapes from the reference)
#define BB  512      // batch
#define HH  512      // hidden
#define YDM 127      // y dim
#define ZDM 385      // z1 dim
#define LLN 256      // seq len
#define G3H 1536     // 3*H

__device__ __forceinline__ float sigm(float v) { return 1.f / (1.f + expf(-v)); }

// ---------------- init: s0 = concat(z1,y), s1 = hidden_1, accT = 0 ----------------
__global__ __launch_bounds__(256)
void init_kernel(const float* __restrict__ z1, const float* __restrict__ y,
                 const float* __restrict__ h1,
                 float* __restrict__ s0, float* __restrict__ s1,
                 float* __restrict__ accT)
{
    int idx = blockIdx.x * blockDim.x + threadIdx.x;
    if (idx < BB * HH) {
        int b = idx / HH, h = idx % HH;
        s0[idx] = (h < ZDM) ? z1[b * ZDM + h] : y[b * YDM + (h - ZDM)];
        s1[idx] = h1[idx];
    }
    if (idx < LLN * BB) accT[idx] = 0.f;
}

// ---------------- giy = y @ w_ih1[:,1:].T + b_ih1   [B, 3H], K=127 ----------------
__global__ __launch_bounds__(256)
void giy_kernel(const float* __restrict__ y, const float* __restrict__ w_ih1,
                const float* __restrict__ b_ih1, float* __restrict__ giy)
{
    __shared__ float yt[16][17], wt[16][17];
    int tid = threadIdx.x, tx = tid & 15, ty = tid >> 4;
    int j0 = blockIdx.x * 16, b0 = blockIdx.y * 16;
    float acc = 0.f;
    for (int k0 = 0; k0 < 128; k0 += 16) {
        int k = k0 + tx;
        yt[ty][tx] = (k < YDM) ? y[(b0 + ty) * YDM + k] : 0.f;
        wt[ty][tx] = (k < YDM) ? w_ih1[(j0 + ty) * 128 + 1 + k] : 0.f;
        __syncthreads();
        #pragma unroll
        for (int kk = 0; kk < 16; ++kk)
            acc += yt[ty][kk] * wt[tx][kk];
        __syncthreads();
    }
    giy[(b0 + ty) * G3H + j0 + tx] = acc + b_ih1[j0 + tx];
}

// ---------------- step A: gh1 = s0@w_hh1.T, gh2 = s1@w_hh2.T, fused GRU1 ----------
// tile 32(batch) x 32(h), 256 threads, 2x2 micro-tile per gate, 6 gate matrices.
__global__ __launch_bounds__(256)
void step_a(int t,
            const float* __restrict__ s0_in, const float* __restrict__ s1_in,
            float* __restrict__ s0_out, float* __restrict__ gh2_out,
            const float* __restrict__ w_hh1, const float* __restrict__ w_hh2,
            const float* __restrict__ b_hh1, const float* __restrict__ b_hh2,
            const float* __restrict__ giy, const float* __restrict__ w_ih1,
            const float* __restrict__ x, const float* __restrict__ accT,
            const float* __restrict__ b_fc)
{
    __shared__ float As0[16][34], As1[16][34];
    __shared__ float W1[3][16][34], W2[3][16][34];
    const int tid = threadIdx.x;
    const int tx = tid & 15, ty = tid >> 4;
    const int n0 = blockIdx.x * 32;   // h tile
    const int m0 = blockIdx.y * 32;   // batch tile

    float c1[3][2][2] = {{{0.f}}}, c2[3][2][2] = {{{0.f}}};

    for (int k0 = 0; k0 < HH; k0 += 16) {
        for (int i = tid; i < 512; i += 256) {
            int mm = i >> 4, kk = i & 15;
            As0[kk][mm] = s0_in[(m0 + mm) * HH + k0 + kk];
            As1[kk][mm] = s1_in[(m0 + mm) * HH + k0 + kk];
        }
        #pragma unroll
        for (int g = 0; g < 3; ++g)
            for (int i = tid; i < 512; i += 256) {
                int nn = i >> 4, kk = i & 15;
                W1[g][kk][nn] = w_hh1[(g * HH + n0 + nn) * HH + k0 + kk];
                W2[g][kk][nn] = w_hh2[(g * HH + n0 + nn) * HH + k0 + kk];
            }
        __syncthreads();
        #pragma unroll
        for (int kk = 0; kk < 16; ++kk) {
            float a00 = As0[kk][2 * ty], a01 = As0[kk][2 * ty + 1];
            float a10 = As1[kk][2 * ty], a11 = As1[kk][2 * ty + 1];
            #pragma unroll
            for (int g = 0; g < 3; ++g) {
                float w10 = W1[g][kk][2 * tx], w11 = W1[g][kk][2 * tx + 1];
                float w20 = W2[g][kk][2 * tx], w21 = W2[g][kk][2 * tx + 1];
                c1[g][0][0] += a00 * w10; c1[g][0][1] += a00 * w11;
                c1[g][1][0] += a01 * w10; c1[g][1][1] += a01 * w11;
                c2[g][0][0] += a10 * w20; c2[g][0][1] += a10 * w21;
                c2[g][1][0] += a11 * w20; c2[g][1][1] += a11 * w21;
            }
        }
        __syncthreads();
    }

    const float bfc = b_fc[0];
    #pragma unroll
    for (int im = 0; im < 2; ++im) {
        int b = m0 + 2 * ty + im;
        float op = (t == 0) ? x[b] : fmaxf(accT[(t - 1) * BB + b] + bfc, 0.f);
        #pragma unroll
        for (int in = 0; in < 2; ++in) {
            int h = n0 + 2 * tx + in;
            float g1r = c1[0][im][in] + b_hh1[h];
            float g1z = c1[1][im][in] + b_hh1[HH + h];
            float g1n = c1[2][im][in] + b_hh1[2 * HH + h];
            // gi1 = giy + out * w_ih1[:,0]  (rank-1: only column 0 of input changes)
            float gir = giy[b * G3H + h]           + op * w_ih1[(h) * 128];
            float giz = giy[b * G3H + HH + h]      + op * w_ih1[(HH + h) * 128];
            float gin = giy[b * G3H + 2 * HH + h]  + op * w_ih1[(2 * HH + h) * 128];
            float r = sigm(gir + g1r);
            float z = sigm(giz + g1z);
            float n = tanhf(gin + r * g1n);
            s0_out[b * HH + h] = (1.f - z) * n + z * s0_in[b * HH + h];
            gh2_out[b * G3H + h]          = c2[0][im][in] + b_hh2[h];
            gh2_out[b * G3H + HH + h]     = c2[1][im][in] + b_hh2[HH + h];
            gh2_out[b * G3H + 2 * HH + h] = c2[2][im][in] + b_hh2[2 * HH + h];
        }
    }
}

// ---------------- step B: gi2 = s0_new@w_ih2.T, fused GRU2 + fc partial ----------
__global__ __launch_bounds__(256)
void step_b(int t,
            const float* __restrict__ s0_new, const float* __restrict__ s1_in,
            float* __restrict__ s1_out, const float* __restrict__ gh2,
            const float* __restrict__ w_ih2, const float* __restrict__ b_ih2,
            const float* __restrict__ w_fc, float* __restrict__ accT)
{
    __shared__ float As[16][34];
    __shared__ float Wt[3][16][34];
    const int tid = threadIdx.x;
    const int tx = tid & 15, ty = tid >> 4;
    const int n0 = blockIdx.x * 32;   // h tile
    const int m0 = blockIdx.y * 32;   // batch tile

    float c[3][2][2] = {{{0.f}}};

    for (int k0 = 0; k0 < HH; k0 += 16) {
        for (int i = tid; i < 512; i += 256) {
            int mm = i >> 4, kk = i & 15;
            As[kk][mm] = s0_new[(m0 + mm) * HH + k0 + kk];
        }
        #pragma unroll
        for (int g = 0; g < 3; ++g)
            for (int i = tid; i < 512; i += 256) {
                int nn = i >> 4, kk = i & 15;
                Wt[g][kk][nn] = w_ih2[(g * HH + n0 + nn) * HH + k0 + kk];
            }
        __syncthreads();
        #pragma unroll
        for (int kk = 0; kk < 16; ++kk) {
            float a0 = As[kk][2 * ty], a1 = As[kk][2 * ty + 1];
            #pragma unroll
            for (int g = 0; g < 3; ++g) {
                float w0 = Wt[g][kk][2 * tx], w1 = Wt[g][kk][2 * tx + 1];
                c[g][0][0] += a0 * w0; c[g][0][1] += a0 * w1;
                c[g][1][0] += a1 * w0; c[g][1][1] += a1 * w1;
            }
        }
        __syncthreads();
    }

    float p0 = 0.f, p1 = 0.f;
    #pragma unroll
    for (int im = 0; im < 2; ++im) {
        int b = m0 + 2 * ty + im;
        #pragma unroll
        for (int in = 0; in < 2; ++in) {
            int h = n0 + 2 * tx + in;
            float gr = c[0][im][in] + b_ih2[h];
            float gz = c[1][im][in] + b_ih2[HH + h];
            float gn = c[2][im][in] + b_ih2[2 * HH + h];
            float hr = gh2[b * G3H + h];
            float hz = gh2[b * G3H + HH + h];
            float hn = gh2[b * G3H + 2 * HH + h];
            float r = sigm(gr + hr);
            float z = sigm(gz + hz);
            float n = tanhf(gn + r * hn);
            float s1n = (1.f - z) * n + z * s1_in[b * HH + h];
            s1_out[b * HH + h] = s1n;
            float contrib = s1n * w_fc[h];
            if (im == 0) p0 += contrib; else p1 += contrib;
        }
    }
    // reduce across the 16 tx lanes (lanes differing in low 4 bits of lane id)
    #pragma unroll
    for (int off = 1; off < 16; off <<= 1) {
        p0 += __shfl_xor(p0, off);
        p1 += __shfl_xor(p1, off);
    }
    if (tx == 0) {
        atomicAdd(&accT[t * BB + m0 + 2 * ty],     p0);
        atomicAdd(&accT[t * BB + m0 + 2 * ty + 1], p1);
    }
}

// ---------------- final: d_out[b*L + t] = relu(accT[t][b] + b_fc) ----------------
__global__ __launch_bounds__(256)
void out_kernel(const float* __restrict__ accT, const float* __restrict__ b_fc,
                float* __restrict__ out)
{
    int idx = blockIdx.x * blockDim.x + threadIdx.x;
    if (idx < BB * LLN) {
        int b = idx / LLN, t = idx % LLN;
        out[idx] = fmaxf(accT[t * BB + b] + b_fc[0], 0.f);
    }
}

extern "C" void kernel_launch(void* const* d_in, const int* in_sizes, int n_in,
                              void* d_out, int out_size, void* d_ws, size_t ws_size,
                              hipStream_t stream)
{
    const float* z1    = (const float*)d_in[0];
    const float* y     = (const float*)d_in[1];
    const float* x     = (const float*)d_in[2];
    const float* h1    = (const float*)d_in[3];
    const float* w_ih1 = (const float*)d_in[4];
    const float* w_hh1 = (const float*)d_in[5];
    const float* b_ih1 = (const float*)d_in[6];
    const float* b_hh1 = (const float*)d_in[7];
    const float* w_ih2 = (const float*)d_in[8];
    const float* w_hh2 = (const float*)d_in[9];
    const float* b_ih2 = (const float*)d_in[10];
    const float* b_hh2 = (const float*)d_in[11];
    const float* w_fc  = (const float*)d_in[12];
    const float* b_fc  = (const float*)d_in[13];
    (void)in_sizes; (void)n_in; (void)out_size; (void)ws_size;

    float* ws   = (float*)d_ws;
    float* giy  = ws;                    // B*3H
    float* s0a  = giy + BB * G3H;        // B*H
    float* s0b  = s0a + BB * HH;
    float* s1a  = s0b + BB * HH;
    float* s1b  = s1a + BB * HH;
    float* gh2  = s1b + BB * HH;         // B*3H
    float* accT = gh2 + BB * G3H;        // L*B

    init_kernel<<<dim3((BB * HH + 255) / 256), dim3(256), 0, stream>>>(z1, y, h1, s0a, s1a, accT);
    giy_kernel<<<dim3(G3H / 16, BB / 16), dim3(256), 0, stream>>>(y, w_ih1, b_ih1, giy);

    for (int t = 0; t < LLN; ++t) {
        const float* s0c = (t & 1) ? s0b : s0a;
        float*       s0n = (t & 1) ? s0a : s0b;
        const float* s1c = (t & 1) ? s1b : s1a;
        float*       s1n = (t & 1) ? s1a : s1b;
        step_a<<<dim3(16, 16), dim3(256), 0, stream>>>(t, s0c, s1c, s0n, gh2,
                w_hh1, w_hh2, b_hh1, b_hh2, giy, w_ih1, x, accT, b_fc);
        step_b<<<dim3(16, 16), dim3(256), 0, stream>>>(t, s0n, s1c, s1n, gh2,
                w_ih2, b_ih2, w_fc, accT);
    }
    out_kernel<<<dim3((BB * LLN + 255) / 256), dim3(256), 0, stream>>>(accT, b_fc, (float*)d_out);
}

// Round 2
// 38724.054 us; speedup vs baseline: 1.1235x; 1.1235x over previous
//
#include <hip/hip_runtime.h>
#include <hip/hip_cooperative_groups.h>
#include <math.h>

namespace cg = cooperative_groups;

#define NB   256      // blocks (1 per CU)
#define NT   256      // threads per block (4 waves)
#define BSZ  512      // batch
#define HSZ  512      // hidden
#define LSEQ 256      // sequence length
#define G3H  1536

typedef __attribute__((ext_vector_type(8))) short sh8;   // 8 bf16 = one MFMA frag
typedef __attribute__((ext_vector_type(4))) float f4;    // MFMA acc

#define MFMA(a,b,c) __builtin_amdgcn_mfma_f32_16x16x32_bf16((a),(b),(c),0,0,0)

__device__ __forceinline__ float bf2f(unsigned short u) {
    union { unsigned int i; float f; } v; v.i = ((unsigned int)u) << 16; return v.f;
}
__device__ __forceinline__ unsigned short f2bf(float f) {
    union { float f; unsigned int i; } v; v.f = f;
    unsigned int r = v.i + 0x7fffu + ((v.i >> 16) & 1u);   // round-to-nearest-even
    return (unsigned short)(r >> 16);
}
__device__ __forceinline__ float sigm(float v) { return 1.f / (1.f + __expf(-v)); }
__device__ __forceinline__ float tanh_(float v) { return 1.f - 2.f / (1.f + __expf(2.f * v)); }

struct P {
    const float *z1, *y, *x, *h1;
    const float *w_ih1, *w_hh1, *b_ih1, *b_hh1;
    const float *w_ih2, *w_hh2, *b_ih2, *b_hh2;
    const float *w_fc, *b_fc;
    unsigned short *wb1, *wb2, *wbI;        // bf16 weights [1536][512]
    unsigned short *giy;                     // bf16 [512][1536]  (y-part of gi1 + b_ih1)
    unsigned short *s0h[2], *s0l[2];         // bf16 hi/lo state ping-pong [512][512]
    unsigned short *s1h[2], *s1l[2];
    float *accT;                             // [256][512] fc accumulators
    float *out;                              // [512][256]
};

__global__ __launch_bounds__(NT, 1) void rnn_kernel(P p)
{
    cg::grid_group grid = cg::this_grid();
    const int tid  = threadIdx.x;
    const int bid  = blockIdx.x;
    const int gtid = bid * NT + tid;

    // ================= init phase (rebuilt every call; ws is poisoned) =================
    for (int i = gtid; i < G3H * HSZ; i += NB * NT) {
        p.wb1[i] = f2bf(p.w_hh1[i]);
        p.wb2[i] = f2bf(p.w_hh2[i]);
        p.wbI[i] = f2bf(p.w_ih2[i]);
    }
    for (int i = gtid; i < BSZ * HSZ; i += NB * NT) {
        int b = i >> 9, hh = i & 511;
        float v0 = (hh < 385) ? p.z1[b * 385 + hh] : p.y[b * 127 + (hh - 385)];
        unsigned short u = f2bf(v0);
        p.s0h[0][i] = u; p.s0l[0][i] = f2bf(v0 - bf2f(u));
        float v1 = p.h1[i];
        u = f2bf(v1);
        p.s1h[0][i] = u; p.s1l[0][i] = f2bf(v1 - bf2f(u));
    }
    for (int i = gtid; i < LSEQ * BSZ; i += NB * NT) p.accT[i] = 0.f;
    // giy[b][j] = b_ih1[j] + sum_k y[b,k] * w_ih1[j, 1+k]   (one-time, K=127, fp32)
    for (int i = gtid; i < BSZ * G3H; i += NB * NT) {
        int b = i / G3H, j = i - b * G3H;
        float a = p.b_ih1[j];
        const float* yr = p.y + b * 127;
        const float* wr = p.w_ih1 + j * 128 + 1;
        #pragma unroll 4
        for (int k = 0; k < 127; ++k) a += yr[k] * wr[k];
        p.giy[i] = f2bf(a);
    }
    __threadfence();
    grid.sync();

    // ================= per-thread geometry =================
    const int lane = tid & 63, w = tid >> 6;       // wave id 0..3
    const int m = lane & 15, quad = lane >> 4;
    const int hx = bid & 31, by = bid >> 5;        // 32 h-tiles x 8 b-tiles
    const int h0 = hx * 16, b0 = by * 64 + w * 16; // wave's 16x16 D-tile origin
    const int h  = h0 + m;                         // this lane's output column
    const int bA = b0 + m;                         // this lane's A-frag row
    const int bD = b0 + quad * 4;                  // D-row base (rows bD..bD+3)
    const float bfc = p.b_fc[0];

    const int hq0 = h, hq1 = HSZ + h, hq2 = 2 * HSZ + h;
    const float bh1v0 = p.b_hh1[hq0], bh1v1 = p.b_hh1[hq1], bh1v2 = p.b_hh1[hq2];
    const float bi2v0 = p.b_ih2[hq0], bi2v1 = p.b_ih2[hq1], bi2v2 = p.b_ih2[hq2];
    const float bh2v0 = p.b_hh2[hq0], bh2v1 = p.b_hh2[hq1], bh2v2 = p.b_hh2[hq2];
    const float w0c0 = p.w_ih1[(size_t)hq0 * 128];
    const float w0c1 = p.w_ih1[(size_t)hq1 * 128];
    const float w0c2 = p.w_ih1[(size_t)hq2 * 128];
    const float wfcv = p.w_fc[h];

    float gyv[4][3];   // t-invariant giy values for this thread's 4 output rows
    #pragma unroll
    for (int r = 0; r < 4; ++r) {
        gyv[r][0] = bf2f(p.giy[(size_t)(bD + r) * G3H + hq0]);
        gyv[r][1] = bf2f(p.giy[(size_t)(bD + r) * G3H + hq1]);
        gyv[r][2] = bf2f(p.giy[(size_t)(bD + r) * G3H + hq2]);
    }
    // weight frag pointers (row-major [1536][512] bf16; 64 sh8 per row)
    const sh8* W1r = (const sh8*)p.wb1 + (size_t)hq0 * 64;
    const sh8* W1z = (const sh8*)p.wb1 + (size_t)hq1 * 64;
    const sh8* W1n = (const sh8*)p.wb1 + (size_t)hq2 * 64;
    const sh8* W2r = (const sh8*)p.wb2 + (size_t)hq0 * 64;
    const sh8* W2z = (const sh8*)p.wb2 + (size_t)hq1 * 64;
    const sh8* W2n = (const sh8*)p.wb2 + (size_t)hq2 * 64;
    const sh8* WIr = (const sh8*)p.wbI + (size_t)hq0 * 64;
    const sh8* WIz = (const sh8*)p.wbI + (size_t)hq1 * 64;
    const sh8* WIn = (const sh8*)p.wbI + (size_t)hq2 * 64;

    // ================= recurrent loop =================
    #pragma clang loop unroll(disable)
    for (int t = 0; t < LSEQ; ++t) {
        const int pi = t & 1, po = pi ^ 1;

        // ---------- phase A: gh1 = s0 @ w_hh1^T, fuse GRU1 -> s0_new ----------
        {
            const unsigned short* sh_ = p.s0h[pi];
            const unsigned short* sl_ = p.s0l[pi];
            const sh8* Ah = (const sh8*)sh_ + (size_t)bA * 64;
            const sh8* Al = (const sh8*)sl_ + (size_t)bA * 64;
            f4 a0 = {0.f,0.f,0.f,0.f}, a1 = a0, a2 = a0;
            #pragma unroll
            for (int ks = 0; ks < 16; ++ks) {
                const int fi = ks * 4 + quad;
                sh8 fh = Ah[fi], fl = Al[fi];
                sh8 w_r = W1r[fi], w_z = W1z[fi], w_n = W1n[fi];
                a0 = MFMA(fh, w_r, a0); a0 = MFMA(fl, w_r, a0);
                a1 = MFMA(fh, w_z, a1); a1 = MFMA(fl, w_z, a1);
                a2 = MFMA(fh, w_n, a2); a2 = MFMA(fl, w_n, a2);
            }
            unsigned short* oh = p.s0h[po];
            unsigned short* ol = p.s0l[po];
            #pragma unroll
            for (int r = 0; r < 4; ++r) {
                int b = bD + r;
                float o = (t == 0) ? p.x[b] : fmaxf(p.accT[(t - 1) * BSZ + b] + bfc, 0.f);
                float rr = sigm(gyv[r][0] + o * w0c0 + a0[r] + bh1v0);
                float zz = sigm(gyv[r][1] + o * w0c1 + a1[r] + bh1v1);
                float hn = a2[r] + bh1v2;
                float nn = tanh_(gyv[r][2] + o * w0c2 + rr * hn);
                size_t ix = (size_t)b * HSZ + h;
                float so = bf2f(sh_[ix]) + bf2f(sl_[ix]);
                float sn = (1.f - zz) * nn + zz * so;
                unsigned short u = f2bf(sn);
                oh[ix] = u; ol[ix] = f2bf(sn - bf2f(u));
            }
        }
        __threadfence();
        grid.sync();

        // ---------- phase B: gi2 = s0_new @ w_ih2^T, gh2 = s1 @ w_hh2^T, GRU2 + fc ----------
        {
            const unsigned short* sh_ = p.s1h[pi];
            const unsigned short* sl_ = p.s1l[pi];
            const sh8* Aih = (const sh8*)p.s0h[po] + (size_t)bA * 64;  // s0_new
            const sh8* Ail = (const sh8*)p.s0l[po] + (size_t)bA * 64;
            const sh8* Ahh = (const sh8*)sh_ + (size_t)bA * 64;        // s1_old
            const sh8* Ahl = (const sh8*)sl_ + (size_t)bA * 64;
            f4 ci0 = {0.f,0.f,0.f,0.f}, ci1 = ci0, ci2 = ci0;
            f4 ch0 = ci0, ch1 = ci0, ch2 = ci0;
            #pragma unroll
            for (int ks = 0; ks < 16; ++ks) {
                const int fi = ks * 4 + quad;
                sh8 ih = Aih[fi], il = Ail[fi];
                sh8 hh = Ahh[fi], hl = Ahl[fi];
                sh8 wir = WIr[fi], wiz = WIz[fi], win = WIn[fi];
                sh8 whr = W2r[fi], whz = W2z[fi], whn = W2n[fi];
                ci0 = MFMA(ih, wir, ci0); ci0 = MFMA(il, wir, ci0);
                ci1 = MFMA(ih, wiz, ci1); ci1 = MFMA(il, wiz, ci1);
                ci2 = MFMA(ih, win, ci2); ci2 = MFMA(il, win, ci2);
                ch0 = MFMA(hh, whr, ch0); ch0 = MFMA(hl, whr, ch0);
                ch1 = MFMA(hh, whz, ch1); ch1 = MFMA(hl, whz, ch1);
                ch2 = MFMA(hh, whn, ch2); ch2 = MFMA(hl, whn, ch2);
            }
            unsigned short* oh = p.s1h[po];
            unsigned short* ol = p.s1l[po];
            #pragma unroll
            for (int r = 0; r < 4; ++r) {
                int b = bD + r;
                float rr = sigm(ci0[r] + bi2v0 + ch0[r] + bh2v0);
                float zz = sigm(ci1[r] + bi2v1 + ch1[r] + bh2v1);
                float nn = tanh_(ci2[r] + bi2v2 + rr * (ch2[r] + bh2v2));
                size_t ix = (size_t)b * HSZ + h;
                float so = bf2f(sh_[ix]) + bf2f(sl_[ix]);
                float sn = (1.f - zz) * nn + zz * so;
                unsigned short u = f2bf(sn);
                oh[ix] = u; ol[ix] = f2bf(sn - bf2f(u));
                float c = sn * wfcv;
                c += __shfl_xor(c, 1); c += __shfl_xor(c, 2);
                c += __shfl_xor(c, 4); c += __shfl_xor(c, 8);
                if (m == 0) atomicAdd(&p.accT[t * BSZ + b], c);
            }
        }
        __threadfence();
        grid.sync();
    }

    // ================= epilogue: out[b][t] = relu(accT[t][b] + b_fc) =================
    for (int i = gtid; i < BSZ * LSEQ; i += NB * NT) {
        int b = i >> 8, t = i & 255;
        p.out[i] = fmaxf(p.accT[t * BSZ + b] + bfc, 0.f);
    }
}

extern "C" void kernel_launch(void* const* d_in, const int* in_sizes, int n_in,
                              void* d_out, int out_size, void* d_ws, size_t ws_size,
                              hipStream_t stream)
{
    (void)in_sizes; (void)n_in; (void)out_size; (void)ws_size;
    P p;
    p.z1    = (const float*)d_in[0];
    p.y     = (const float*)d_in[1];
    p.x     = (const float*)d_in[2];
    p.h1    = (const float*)d_in[3];
    p.w_ih1 = (const float*)d_in[4];
    p.w_hh1 = (const float*)d_in[5];
    p.b_ih1 = (const float*)d_in[6];
    p.b_hh1 = (const float*)d_in[7];
    p.w_ih2 = (const float*)d_in[8];
    p.w_hh2 = (const float*)d_in[9];
    p.b_ih2 = (const float*)d_in[10];
    p.b_hh2 = (const float*)d_in[11];
    p.w_fc  = (const float*)d_in[12];
    p.b_fc  = (const float*)d_in[13];

    unsigned short* ws = (unsigned short*)d_ws;
    size_t off = 0;
    p.wb1 = ws + off; off += (size_t)G3H * HSZ;
    p.wb2 = ws + off; off += (size_t)G3H * HSZ;
    p.wbI = ws + off; off += (size_t)G3H * HSZ;
    p.giy = ws + off; off += (size_t)BSZ * G3H;
    for (int i = 0; i < 2; ++i) { p.s0h[i] = ws + off; off += (size_t)BSZ * HSZ; }
    for (int i = 0; i < 2; ++i) { p.s0l[i] = ws + off; off += (size_t)BSZ * HSZ; }
    for (int i = 0; i < 2; ++i) { p.s1h[i] = ws + off; off += (size_t)BSZ * HSZ; }
    for (int i = 0; i < 2; ++i) { p.s1l[i] = ws + off; off += (size_t)BSZ * HSZ; }
    p.accT = (float*)(ws + off);
    p.out  = (float*)d_out;

    void* args[] = { &p };
    hipLaunchCooperativeKernel((const void*)rnn_kernel, dim3(NB), dim3(NT), args, 0, stream);
}

// Round 3
// 12026.070 us; speedup vs baseline: 3.6177x; 3.2200x over previous
//
#include <hip/hip_runtime.h>
#include <math.h>

#define NB   256      // persistent blocks (1 per CU)
#define NT   256      // threads per block (4 waves)
#define BSZ  512      // batch
#define HSZ  512      // hidden
#define LSEQ 256      // sequence length
#define G3H  1536

typedef __attribute__((ext_vector_type(8))) short sh8;   // 8 bf16 = one MFMA frag
typedef __attribute__((ext_vector_type(4))) float f4;    // MFMA acc

#define MFMA(a,b,c) __builtin_amdgcn_mfma_f32_16x16x32_bf16((a),(b),(c),0,0,0)

__device__ __forceinline__ float bf2f(unsigned short u) {
    union { unsigned int i; float f; } v; v.i = ((unsigned int)u) << 16; return v.f;
}
__device__ __forceinline__ unsigned short f2bf(float f) {
    union { float f; unsigned int i; } v; v.f = f;
    unsigned int r = v.i + 0x7fffu + ((v.i >> 16) & 1u);   // RNE
    return (unsigned short)(r >> 16);
}
__device__ __forceinline__ float sigm(float v) { return 1.f / (1.f + __expf(-v)); }
__device__ __forceinline__ float tanh_(float v) { return 1.f - 2.f / (1.f + __expf(2.f * v)); }

struct P {
    const float *z1, *y, *x, *h1;
    const float *w_ih1, *w_hh1, *b_ih1, *b_hh1;
    const float *w_ih2, *w_hh2, *b_ih2, *b_hh2;
    const float *w_fc, *b_fc;
    unsigned short *wb1, *wb2, *wbI;        // bf16 weights [1536][512]
    unsigned short *giy;                     // bf16 [512][1536]
    unsigned short *s0h[2], *s0l[2];         // bf16 hi/lo state ping-pong [512][512]
    unsigned short *s1h[2], *s1l[2];
    float *accT;                             // [256][512]
    unsigned *bar;                           // 8 group counters, 256B apart
    float *out;                              // [512][256]
};

// ---------------- init kernel (normal launch; stream order = fence) ----------------
__global__ __launch_bounds__(256) void init_k(P p)
{
    int gt = blockIdx.x * 256 + threadIdx.x;
    int stride = gridDim.x * 256;
    for (int i = gt; i < G3H * HSZ; i += stride) {
        p.wb1[i] = f2bf(p.w_hh1[i]);
        p.wb2[i] = f2bf(p.w_hh2[i]);
        p.wbI[i] = f2bf(p.w_ih2[i]);
    }
    for (int i = gt; i < BSZ * HSZ; i += stride) {
        int b = i >> 9, hh = i & 511;
        float v0 = (hh < 385) ? p.z1[b * 385 + hh] : p.y[b * 127 + (hh - 385)];
        unsigned short u = f2bf(v0);
        p.s0h[0][i] = u; p.s0l[0][i] = f2bf(v0 - bf2f(u));
        float v1 = p.h1[i];
        u = f2bf(v1);
        p.s1h[0][i] = u; p.s1l[0][i] = f2bf(v1 - bf2f(u));
    }
    for (int i = gt; i < LSEQ * BSZ; i += stride) p.accT[i] = 0.f;
    for (int i = gt; i < 8 * 64; i += stride) p.bar[i] = 0u;
    for (int i = gt; i < BSZ * G3H; i += stride) {
        int b = i / G3H, j = i - b * G3H;
        float a = p.b_ih1[j];
        const float* yr = p.y + b * 127;
        const float* wr = p.w_ih1 + j * 128 + 1;
        #pragma unroll 4
        for (int k = 0; k < 127; ++k) a += yr[k] * wr[k];
        p.giy[i] = f2bf(a);
    }
}

// ---------------- group barrier: 32 blocks, monotonic counter ----------------
__device__ __forceinline__ void gbar(unsigned* cnt, unsigned tgt)
{
    __syncthreads();   // all waves' stores at least in local L2 (per-wave vmcnt0)
    if (threadIdx.x == 0) {
        // release: wb dirty L2 to coherence point, then bump
        __hip_atomic_fetch_add(cnt, 1u, __ATOMIC_RELEASE, __HIP_MEMORY_SCOPE_AGENT);
        while (__hip_atomic_load(cnt, __ATOMIC_RELAXED, __HIP_MEMORY_SCOPE_AGENT) < tgt)
            __builtin_amdgcn_s_sleep(1);
        // acquire: invalidate L1+L2 so fresh data is visible
        __builtin_amdgcn_fence(__ATOMIC_ACQUIRE, "agent");
    }
    __syncthreads();
}

__global__ __launch_bounds__(NT, 1) void rnn_kernel(P p)
{
    __shared__ __align__(16) unsigned short Wlds[3][16][520];  // phase-A weights, padded

    const int tid  = threadIdx.x;
    const int bid  = blockIdx.x;
    const int lane = tid & 63, w = tid >> 6;
    const int m = lane & 15, quad = lane >> 4;
    const int hx = bid & 31, by = bid >> 5;        // 32 h-tiles x 8 groups
    const int h0 = hx * 16, b0 = by * 64 + w * 16;
    const int h  = h0 + m;
    const int bA = b0 + m;
    const int bD = b0 + quad * 4;
    unsigned* cnt = p.bar + by * 64;

    // stage phase-A weights (w_hh1 rows for this block's 16 h-cols) into LDS
    for (int c = tid; c < 3072; c += NT) {
        int row = c >> 6, ch = c & 63;
        int g = row >> 4, lc = row & 15;
        const sh8* src = (const sh8*)(p.wb1 + (size_t)(g * HSZ + h0 + lc) * HSZ) + ch;
        *(sh8*)&Wlds[g][lc][ch * 8] = *src;
    }
    __syncthreads();

    const float bfc = p.b_fc[0];
    const int hq0 = h, hq1 = HSZ + h, hq2 = 2 * HSZ + h;
    const float bh1v0 = p.b_hh1[hq0], bh1v1 = p.b_hh1[hq1], bh1v2 = p.b_hh1[hq2];
    const float bi2v0 = p.b_ih2[hq0], bi2v1 = p.b_ih2[hq1], bi2v2 = p.b_ih2[hq2];
    const float bh2v0 = p.b_hh2[hq0], bh2v1 = p.b_hh2[hq1], bh2v2 = p.b_hh2[hq2];
    const float w0c0 = p.w_ih1[(size_t)hq0 * 128];
    const float w0c1 = p.w_ih1[(size_t)hq1 * 128];
    const float w0c2 = p.w_ih1[(size_t)hq2 * 128];
    const float wfcv = p.w_fc[h];

    float gyv[4][3];
    #pragma unroll
    for (int r = 0; r < 4; ++r) {
        gyv[r][0] = bf2f(p.giy[(size_t)(bD + r) * G3H + hq0]);
        gyv[r][1] = bf2f(p.giy[(size_t)(bD + r) * G3H + hq1]);
        gyv[r][2] = bf2f(p.giy[(size_t)(bD + r) * G3H + hq2]);
    }
    // phase-B weight frag pointers (global; stream from L2/L3)
    const sh8* W2r = (const sh8*)p.wb2 + (size_t)hq0 * 64;
    const sh8* W2z = (const sh8*)p.wb2 + (size_t)hq1 * 64;
    const sh8* W2n = (const sh8*)p.wb2 + (size_t)hq2 * 64;
    const sh8* WIr = (const sh8*)p.wbI + (size_t)hq0 * 64;
    const sh8* WIz = (const sh8*)p.wbI + (size_t)hq1 * 64;
    const sh8* WIn = (const sh8*)p.wbI + (size_t)hq2 * 64;

    unsigned tgt = 0;

    #pragma clang loop unroll(disable)
    for (int t = 0; t < LSEQ; ++t) {
        const int pi = t & 1, po = pi ^ 1;

        // ---------- phase A: gh1 = s0 @ w_hh1^T (weights from LDS), GRU1 -> s0_new ----------
        {
            const unsigned short* sh_ = p.s0h[pi];
            const unsigned short* sl_ = p.s0l[pi];
            const sh8* Ah = (const sh8*)sh_ + (size_t)bA * 64;
            const sh8* Al = (const sh8*)sl_ + (size_t)bA * 64;
            sh8 ah[16], al[16];
            #pragma unroll
            for (int ks = 0; ks < 16; ++ks) { ah[ks] = Ah[ks * 4 + quad]; al[ks] = Al[ks * 4 + quad]; }
            f4 a0 = {0.f,0.f,0.f,0.f}, a1 = a0, a2 = a0;
            #pragma unroll
            for (int ks = 0; ks < 16; ++ks) {
                const int fo = (ks * 4 + quad) * 8;
                sh8 w_r = *(const sh8*)&Wlds[0][m][fo];
                sh8 w_z = *(const sh8*)&Wlds[1][m][fo];
                sh8 w_n = *(const sh8*)&Wlds[2][m][fo];
                a0 = MFMA(ah[ks], w_r, a0); a0 = MFMA(al[ks], w_r, a0);
                a1 = MFMA(ah[ks], w_z, a1); a1 = MFMA(al[ks], w_z, a1);
                a2 = MFMA(ah[ks], w_n, a2); a2 = MFMA(al[ks], w_n, a2);
            }
            unsigned short* oh = p.s0h[po];
            unsigned short* ol = p.s0l[po];
            #pragma unroll
            for (int r = 0; r < 4; ++r) {
                int b = bD + r;
                float o = (t == 0) ? p.x[b] : fmaxf(p.accT[(t - 1) * BSZ + b] + bfc, 0.f);
                float rr = sigm(gyv[r][0] + o * w0c0 + a0[r] + bh1v0);
                float zz = sigm(gyv[r][1] + o * w0c1 + a1[r] + bh1v1);
                float nn = tanh_(gyv[r][2] + o * w0c2 + rr * (a2[r] + bh1v2));
                size_t ix = (size_t)b * HSZ + h;
                float so = bf2f(sh_[ix]) + bf2f(sl_[ix]);
                float sn = (1.f - zz) * nn + zz * so;
                unsigned short u = f2bf(sn);
                oh[ix] = u; ol[ix] = f2bf(sn - bf2f(u));
            }
        }
        tgt += 32; gbar(cnt, tgt);

        // ---------- phase B: gi2 = s0_new @ w_ih2^T, gh2 = s1 @ w_hh2^T, GRU2 + fc ----------
        {
            const unsigned short* sh_ = p.s1h[pi];
            const unsigned short* sl_ = p.s1l[pi];
            const sh8* Aih = (const sh8*)p.s0h[po] + (size_t)bA * 64;
            const sh8* Ail = (const sh8*)p.s0l[po] + (size_t)bA * 64;
            const sh8* Ahh = (const sh8*)sh_ + (size_t)bA * 64;
            const sh8* Ahl = (const sh8*)sl_ + (size_t)bA * 64;

            sh8 ih[16], il[16];
            #pragma unroll
            for (int ks = 0; ks < 16; ++ks) { ih[ks] = Aih[ks * 4 + quad]; il[ks] = Ail[ks * 4 + quad]; }
            f4 ci0 = {0.f,0.f,0.f,0.f}, ci1 = ci0, ci2 = ci0;
            #pragma unroll
            for (int ks = 0; ks < 16; ++ks) {
                const int fi = ks * 4 + quad;
                sh8 wir = WIr[fi], wiz = WIz[fi], win = WIn[fi];
                ci0 = MFMA(ih[ks], wir, ci0); ci0 = MFMA(il[ks], wir, ci0);
                ci1 = MFMA(ih[ks], wiz, ci1); ci1 = MFMA(il[ks], wiz, ci1);
                ci2 = MFMA(ih[ks], win, ci2); ci2 = MFMA(il[ks], win, ci2);
            }
            sh8 hh[16], hl[16];
            #pragma unroll
            for (int ks = 0; ks < 16; ++ks) { hh[ks] = Ahh[ks * 4 + quad]; hl[ks] = Ahl[ks * 4 + quad]; }
            f4 ch0 = {0.f,0.f,0.f,0.f}, ch1 = ch0, ch2 = ch0;
            #pragma unroll
            for (int ks = 0; ks < 16; ++ks) {
                const int fi = ks * 4 + quad;
                sh8 whr = W2r[fi], whz = W2z[fi], whn = W2n[fi];
                ch0 = MFMA(hh[ks], whr, ch0); ch0 = MFMA(hl[ks], whr, ch0);
                ch1 = MFMA(hh[ks], whz, ch1); ch1 = MFMA(hl[ks], whz, ch1);
                ch2 = MFMA(hh[ks], whn, ch2); ch2 = MFMA(hl[ks], whn, ch2);
            }
            unsigned short* oh = p.s1h[po];
            unsigned short* ol = p.s1l[po];
            #pragma unroll
            for (int r = 0; r < 4; ++r) {
                int b = bD + r;
                float rr = sigm(ci0[r] + bi2v0 + ch0[r] + bh2v0);
                float zz = sigm(ci1[r] + bi2v1 + ch1[r] + bh2v1);
                float nn = tanh_(ci2[r] + bi2v2 + rr * (ch2[r] + bh2v2));
                size_t ix = (size_t)b * HSZ + h;
                float so = bf2f(sh_[ix]) + bf2f(sl_[ix]);
                float sn = (1.f - zz) * nn + zz * so;
                unsigned short u = f2bf(sn);
                oh[ix] = u; ol[ix] = f2bf(sn - bf2f(u));
                float c = sn * wfcv;
                c += __shfl_xor(c, 1); c += __shfl_xor(c, 2);
                c += __shfl_xor(c, 4); c += __shfl_xor(c, 8);
                if (m == 0) atomicAdd(&p.accT[t * BSZ + b], c);
            }
        }
        tgt += 32; gbar(cnt, tgt);
    }

    // ---------- epilogue: group-local out write ----------
    {
        const int r = bid & 31;
        for (int e = tid; e < 512; e += NT) {
            int idx = r * 512 + e;                 // [0, 16384) within group slice
            int bl = idx >> 8, t = idx & 255;
            int b = by * 64 + bl;
            p.out[(size_t)b * 256 + t] = fmaxf(p.accT[t * BSZ + b] + bfc, 0.f);
        }
    }
}

extern "C" void kernel_launch(void* const* d_in, const int* in_sizes, int n_in,
                              void* d_out, int out_size, void* d_ws, size_t ws_size,
                              hipStream_t stream)
{
    (void)in_sizes; (void)n_in; (void)out_size; (void)ws_size;
    P p;
    p.z1    = (const float*)d_in[0];
    p.y     = (const float*)d_in[1];
    p.x     = (const float*)d_in[2];
    p.h1    = (const float*)d_in[3];
    p.w_ih1 = (const float*)d_in[4];
    p.w_hh1 = (const float*)d_in[5];
    p.b_ih1 = (const float*)d_in[6];
    p.b_hh1 = (const float*)d_in[7];
    p.w_ih2 = (const float*)d_in[8];
    p.w_hh2 = (const float*)d_in[9];
    p.b_ih2 = (const float*)d_in[10];
    p.b_hh2 = (const float*)d_in[11];
    p.w_fc  = (const float*)d_in[12];
    p.b_fc  = (const float*)d_in[13];

    unsigned short* ws = (unsigned short*)d_ws;
    size_t off = 0;
    p.wb1 = ws + off; off += (size_t)G3H * HSZ;
    p.wb2 = ws + off; off += (size_t)G3H * HSZ;
    p.wbI = ws + off; off += (size_t)G3H * HSZ;
    p.giy = ws + off; off += (size_t)BSZ * G3H;
    for (int i = 0; i < 2; ++i) { p.s0h[i] = ws + off; off += (size_t)BSZ * HSZ; }
    for (int i = 0; i < 2; ++i) { p.s0l[i] = ws + off; off += (size_t)BSZ * HSZ; }
    for (int i = 0; i < 2; ++i) { p.s1h[i] = ws + off; off += (size_t)BSZ * HSZ; }
    for (int i = 0; i < 2; ++i) { p.s1l[i] = ws + off; off += (size_t)BSZ * HSZ; }
    p.accT = (float*)(ws + off); off += (size_t)LSEQ * BSZ * 2;
    p.bar  = (unsigned*)(ws + off);
    p.out  = (float*)d_out;

    init_k<<<dim3(1024), dim3(256), 0, stream>>>(p);

    void* args[] = { &p };
    hipLaunchCooperativeKernel((const void*)rnn_kernel, dim3(NB), dim3(NT), args, 0, stream);
}

// Round 5
// 7495.232 us; speedup vs baseline: 5.8047x; 1.6045x over previous
//
#include <hip/hip_runtime.h>
#include <hip/hip_cooperative_groups.h>
#include <math.h>

namespace cg = cooperative_groups;

#define NB   256      // persistent blocks (1 per CU)
#define NT   256      // threads per block (4 waves)
#define BSZ  512      // batch
#define HSZ  512      // hidden
#define LSEQ 256      // sequence length
#define G3H  1536

typedef __attribute__((ext_vector_type(8))) short sh8;   // 8 bf16 = one MFMA frag
typedef __attribute__((ext_vector_type(4))) float f4;    // MFMA acc

#define MFMA(a,b,c) __builtin_amdgcn_mfma_f32_16x16x32_bf16((a),(b),(c),0,0,0)
#define AGENT __HIP_MEMORY_SCOPE_AGENT
#define RLX   __ATOMIC_RELAXED

__device__ __forceinline__ float bf2f(unsigned short u) {
    union { unsigned int i; float f; } v; v.i = ((unsigned int)u) << 16; return v.f;
}
__device__ __forceinline__ unsigned short f2bf(float f) {
    union { float f; unsigned int i; } v; v.f = f;
    unsigned int r = v.i + 0x7fffu + ((v.i >> 16) & 1u);   // RNE
    return (unsigned short)(r >> 16);
}
__device__ __forceinline__ float sigm(float v) { return 1.f / (1.f + __expf(-v)); }
__device__ __forceinline__ float tanh_(float v) { return 1.f - 2.f / (1.f + __expf(2.f * v)); }

// accT lives at the coherence point (sc1 atomicAdd); read it with agent atomics
__device__ __forceinline__ float aldf(const float* p) {
    return __hip_atomic_load(p, RLX, AGENT);
}
__device__ __forceinline__ int xcc_id() {
    int x;
    asm volatile("s_getreg_b32 %0, hwreg(HW_REG_XCC_ID)" : "=s"(x));
    return x & 7;
}

struct P {
    const float *z1, *y, *x, *h1;
    const float *w_ih1, *w_hh1, *b_ih1, *b_hh1;
    const float *w_ih2, *w_hh2, *b_ih2, *b_hh2;
    const float *w_fc, *b_fc;
    unsigned short *wb1, *wb2, *wbI;        // bf16 weights [1536][512]
    unsigned short *giy;                     // bf16 [512][1536]
    unsigned short *s0h[2], *s0l[2];         // bf16 hi/lo state ping-pong [512][512]
    unsigned short *s1h[2], *s1l[2];
    float *accT;                             // [256][512]
    unsigned *bar;                           // 8 group counters, 256B apart
    unsigned *claim;                         // 8 per-XCD slot counters
    float *out;                              // [512][256]
};

// ---------------- init kernel (kernel-boundary flush publishes all of this) ------
__global__ __launch_bounds__(256) void init_k(P p)
{
    int gt = blockIdx.x * 256 + threadIdx.x;
    int stride = gridDim.x * 256;
    for (int i = gt; i < G3H * HSZ; i += stride) {
        p.wb1[i] = f2bf(p.w_hh1[i]);
        p.wb2[i] = f2bf(p.w_hh2[i]);
        p.wbI[i] = f2bf(p.w_ih2[i]);
    }
    for (int i = gt; i < BSZ * HSZ; i += stride) {
        int b = i >> 9, hh = i & 511;
        float v0 = (hh < 385) ? p.z1[b * 385 + hh] : p.y[b * 127 + (hh - 385)];
        unsigned short u = f2bf(v0);
        p.s0h[0][i] = u; p.s0l[0][i] = f2bf(v0 - bf2f(u));
        float v1 = p.h1[i];
        u = f2bf(v1);
        p.s1h[0][i] = u; p.s1l[0][i] = f2bf(v1 - bf2f(u));
    }
    for (int i = gt; i < LSEQ * BSZ; i += stride) p.accT[i] = 0.f;
    for (int i = gt; i < 8 * 64; i += stride) p.bar[i] = 0u;
    for (int i = gt; i < 8; i += stride) p.claim[i] = 0u;
    for (int i = gt; i < BSZ * G3H; i += stride) {
        int b = i / G3H, j = i - b * G3H;
        float a = p.b_ih1[j];
        const float* yr = p.y + b * 127;
        const float* wr = p.w_ih1 + j * 128 + 1;
        #pragma unroll 4
        for (int k = 0; k < 127; ++k) a += yr[k] * wr[k];
        p.giy[i] = f2bf(a);
    }
}

// group barrier. fast: group is XCD-local -> stores retire at shared L2; relaxed
// counter at MALL orders arrival; L1-only invalidate on exit. slow: R2's proven
// release/acquire (full cache maintenance).
__device__ __forceinline__ void gbar(unsigned* cnt, unsigned tgt, bool fast)
{
    __syncthreads();   // all waves drain vmcnt(0): stores committed in XCD L2
    if (threadIdx.x == 0) {
        if (fast) {
            __hip_atomic_fetch_add(cnt, 1u, RLX, AGENT);
            while (__hip_atomic_load(cnt, RLX, AGENT) < tgt)
                __builtin_amdgcn_s_sleep(1);
        } else {
            __hip_atomic_fetch_add(cnt, 1u, __ATOMIC_RELEASE, AGENT);
            while (__hip_atomic_load(cnt, RLX, AGENT) < tgt)
                __builtin_amdgcn_s_sleep(1);
            __builtin_amdgcn_fence(__ATOMIC_ACQUIRE, "agent");
        }
    }
    __syncthreads();
    if (fast) {
        // invalidate this CU's L1 so post-barrier loads see the group's L2 data
        asm volatile("buffer_inv sc0\n\ts_waitcnt vmcnt(0)" ::: "memory");
    }
}

__global__ __launch_bounds__(NT, 1) void rnn_kernel(P p)
{
    __shared__ __align__(16) unsigned short Wlds[3][16][520];  // phase-A weights
    __shared__ int s_xcd, s_slot;

    cg::grid_group grid = cg::this_grid();
    const int tid  = threadIdx.x;
    const int bid  = blockIdx.x;

    // ---- runtime XCD-local group formation ----
    if (tid == 0) {
        int x = xcc_id();
        s_xcd = x;
        s_slot = (int)__hip_atomic_fetch_add(&p.claim[x], 1u, RLX, AGENT);
    }
    grid.sync();   // one-time full-coherence rendezvous (claims all visible)

    bool fast = true;
    #pragma unroll
    for (int x = 0; x < 8; ++x)
        fast = fast && (__hip_atomic_load(&p.claim[x], RLX, AGENT) == 32u);

    const int by = fast ? s_xcd  : (bid >> 5);   // batch group (8)
    const int hx = fast ? s_slot : (bid & 31);   // h tile within group (32)

    const int lane = tid & 63, w = tid >> 6;
    const int m = lane & 15, quad = lane >> 4;
    const int h0 = hx * 16, b0 = by * 64 + w * 16;
    const int h  = h0 + m;
    const int bA = b0 + m;
    const int bD = b0 + quad * 4;
    unsigned* cnt = p.bar + by * 64;

    // stage phase-A weights (w_hh1 rows for this block's 16 h-cols) into LDS
    for (int c = tid; c < 3072; c += NT) {
        int row = c >> 6, ch = c & 63;
        int g = row >> 4, lc = row & 15;
        const sh8* src = (const sh8*)(p.wb1 + (size_t)(g * HSZ + h0 + lc) * HSZ) + ch;
        *(sh8*)&Wlds[g][lc][ch * 8] = *src;
    }
    __syncthreads();

    const float bfc = p.b_fc[0];
    const int hq0 = h, hq1 = HSZ + h, hq2 = 2 * HSZ + h;
    const float bh1v0 = p.b_hh1[hq0], bh1v1 = p.b_hh1[hq1], bh1v2 = p.b_hh1[hq2];
    const float bi2v0 = p.b_ih2[hq0], bi2v1 = p.b_ih2[hq1], bi2v2 = p.b_ih2[hq2];
    const float bh2v0 = p.b_hh2[hq0], bh2v1 = p.b_hh2[hq1], bh2v2 = p.b_hh2[hq2];
    const float w0c0 = p.w_ih1[(size_t)hq0 * 128];
    const float w0c1 = p.w_ih1[(size_t)hq1 * 128];
    const float w0c2 = p.w_ih1[(size_t)hq2 * 128];
    const float wfcv = p.w_fc[h];

    float gyv[4][3];
    #pragma unroll
    for (int r = 0; r < 4; ++r) {
        gyv[r][0] = bf2f(p.giy[(size_t)(bD + r) * G3H + hq0]);
        gyv[r][1] = bf2f(p.giy[(size_t)(bD + r) * G3H + hq1]);
        gyv[r][2] = bf2f(p.giy[(size_t)(bD + r) * G3H + hq2]);
    }
    // phase-B weight frag pointers (cached; L2 is never invalidated on fast path)
    const sh8* W2r = (const sh8*)p.wb2 + (size_t)hq0 * 64;
    const sh8* W2z = (const sh8*)p.wb2 + (size_t)hq1 * 64;
    const sh8* W2n = (const sh8*)p.wb2 + (size_t)hq2 * 64;
    const sh8* WIr = (const sh8*)p.wbI + (size_t)hq0 * 64;
    const sh8* WIz = (const sh8*)p.wbI + (size_t)hq1 * 64;
    const sh8* WIn = (const sh8*)p.wbI + (size_t)hq2 * 64;

    unsigned tgt = 0;

    #pragma clang loop unroll(disable)
    for (int t = 0; t < LSEQ; ++t) {
        const int pi = t & 1, po = pi ^ 1;

        // ---------- phase A: gh1 = s0 @ w_hh1^T (weights from LDS), GRU1 -> s0_new ----------
        {
            const unsigned short* sh_ = p.s0h[pi];
            const unsigned short* sl_ = p.s0l[pi];
            const sh8* Ah = (const sh8*)sh_ + (size_t)bA * 64;
            const sh8* Al = (const sh8*)sl_ + (size_t)bA * 64;
            sh8 ah[16], al[16];
            #pragma unroll
            for (int ks = 0; ks < 16; ++ks) { ah[ks] = Ah[ks * 4 + quad]; al[ks] = Al[ks * 4 + quad]; }
            f4 a0 = {0.f,0.f,0.f,0.f}, a1 = a0, a2 = a0;
            #pragma unroll
            for (int ks = 0; ks < 16; ++ks) {
                const int fo = (ks * 4 + quad) * 8;
                sh8 w_r = *(const sh8*)&Wlds[0][m][fo];
                sh8 w_z = *(const sh8*)&Wlds[1][m][fo];
                sh8 w_n = *(const sh8*)&Wlds[2][m][fo];
                a0 = MFMA(ah[ks], w_r, a0); a0 = MFMA(al[ks], w_r, a0);
                a1 = MFMA(ah[ks], w_z, a1); a1 = MFMA(al[ks], w_z, a1);
                a2 = MFMA(ah[ks], w_n, a2); a2 = MFMA(al[ks], w_n, a2);
            }
            unsigned short* oh = p.s0h[po];
            unsigned short* ol = p.s0l[po];
            #pragma unroll
            for (int r = 0; r < 4; ++r) {
                int b = bD + r;
                float o = (t == 0) ? p.x[b]
                                   : fmaxf(aldf(&p.accT[(t - 1) * BSZ + b]) + bfc, 0.f);
                float rr = sigm(gyv[r][0] + o * w0c0 + a0[r] + bh1v0);
                float zz = sigm(gyv[r][1] + o * w0c1 + a1[r] + bh1v1);
                float nn = tanh_(gyv[r][2] + o * w0c2 + rr * (a2[r] + bh1v2));
                size_t ix = (size_t)b * HSZ + h;
                float so = bf2f(sh_[ix]) + bf2f(sl_[ix]);
                float sn = (1.f - zz) * nn + zz * so;
                unsigned short u = f2bf(sn);
                oh[ix] = u; ol[ix] = f2bf(sn - bf2f(u));
            }
        }
        tgt += 32; gbar(cnt, tgt, fast);

        // ---------- phase B: gi2 = s0_new @ w_ih2^T, gh2 = s1 @ w_hh2^T, GRU2 + fc ------
        {
            const unsigned short* sh_ = p.s1h[pi];
            const unsigned short* sl_ = p.s1l[pi];
            const sh8* Aih = (const sh8*)p.s0h[po] + (size_t)bA * 64;
            const sh8* Ail = (const sh8*)p.s0l[po] + (size_t)bA * 64;
            const sh8* Ahh = (const sh8*)sh_ + (size_t)bA * 64;
            const sh8* Ahl = (const sh8*)sl_ + (size_t)bA * 64;

            sh8 ih[16], il[16];
            #pragma unroll
            for (int ks = 0; ks < 16; ++ks) { ih[ks] = Aih[ks * 4 + quad]; il[ks] = Ail[ks * 4 + quad]; }
            f4 ci0 = {0.f,0.f,0.f,0.f}, ci1 = ci0, ci2 = ci0;
            #pragma unroll
            for (int ks = 0; ks < 16; ++ks) {
                const int fi = ks * 4 + quad;
                sh8 wir = WIr[fi], wiz = WIz[fi], win = WIn[fi];
                ci0 = MFMA(ih[ks], wir, ci0); ci0 = MFMA(il[ks], wir, ci0);
                ci1 = MFMA(ih[ks], wiz, ci1); ci1 = MFMA(il[ks], wiz, ci1);
                ci2 = MFMA(ih[ks], win, ci2); ci2 = MFMA(il[ks], win, ci2);
            }
            sh8 hh[16], hl[16];
            #pragma unroll
            for (int ks = 0; ks < 16; ++ks) { hh[ks] = Ahh[ks * 4 + quad]; hl[ks] = Ahl[ks * 4 + quad]; }
            f4 ch0 = {0.f,0.f,0.f,0.f}, ch1 = ch0, ch2 = ch0;
            #pragma unroll
            for (int ks = 0; ks < 16; ++ks) {
                const int fi = ks * 4 + quad;
                sh8 whr = W2r[fi], whz = W2z[fi], whn = W2n[fi];
                ch0 = MFMA(hh[ks], whr, ch0); ch0 = MFMA(hl[ks], whr, ch0);
                ch1 = MFMA(hh[ks], whz, ch1); ch1 = MFMA(hl[ks], whz, ch1);
                ch2 = MFMA(hh[ks], whn, ch2); ch2 = MFMA(hl[ks], whn, ch2);
            }
            unsigned short* oh = p.s1h[po];
            unsigned short* ol = p.s1l[po];
            #pragma unroll
            for (int r = 0; r < 4; ++r) {
                int b = bD + r;
                float rr = sigm(ci0[r] + bi2v0 + ch0[r] + bh2v0);
                float zz = sigm(ci1[r] + bi2v1 + ch1[r] + bh2v1);
                float nn = tanh_(ci2[r] + bi2v2 + rr * (ch2[r] + bh2v2));
                size_t ix = (size_t)b * HSZ + h;
                float so = bf2f(sh_[ix]) + bf2f(sl_[ix]);
                float sn = (1.f - zz) * nn + zz * so;
                unsigned short u = f2bf(sn);
                oh[ix] = u; ol[ix] = f2bf(sn - bf2f(u));
                float c = sn * wfcv;
                c += __shfl_xor(c, 1); c += __shfl_xor(c, 2);
                c += __shfl_xor(c, 4); c += __shfl_xor(c, 8);
                if (m == 0) atomicAdd(&p.accT[t * BSZ + b], c);
            }
        }
        tgt += 32; gbar(cnt, tgt, fast);
    }

    // ---------- epilogue: group-local out write ----------
    {
        const int r = hx;
        for (int e = tid; e < 512; e += NT) {
            int idx = r * 512 + e;
            int bl = idx >> 8, t = idx & 255;
            int b = by * 64 + bl;
            p.out[(size_t)b * 256 + t] = fmaxf(aldf(&p.accT[t * BSZ + b]) + bfc, 0.f);
        }
    }
}

extern "C" void kernel_launch(void* const* d_in, const int* in_sizes, int n_in,
                              void* d_out, int out_size, void* d_ws, size_t ws_size,
                              hipStream_t stream)
{
    (void)in_sizes; (void)n_in; (void)out_size; (void)ws_size;
    P p;
    p.z1    = (const float*)d_in[0];
    p.y     = (const float*)d_in[1];
    p.x     = (const float*)d_in[2];
    p.h1    = (const float*)d_in[3];
    p.w_ih1 = (const float*)d_in[4];
    p.w_hh1 = (const float*)d_in[5];
    p.b_ih1 = (const float*)d_in[6];
    p.b_hh1 = (const float*)d_in[7];
    p.w_ih2 = (const float*)d_in[8];
    p.w_hh2 = (const float*)d_in[9];
    p.b_ih2 = (const float*)d_in[10];
    p.b_hh2 = (const float*)d_in[11];
    p.w_fc  = (const float*)d_in[12];
    p.b_fc  = (const float*)d_in[13];

    unsigned short* ws = (unsigned short*)d_ws;
    size_t off = 0;
    p.wb1 = ws + off; off += (size_t)G3H * HSZ;
    p.wb2 = ws + off; off += (size_t)G3H * HSZ;
    p.wbI = ws + off; off += (size_t)G3H * HSZ;
    p.giy = ws + off; off += (size_t)BSZ * G3H;
    for (int i = 0; i < 2; ++i) { p.s0h[i] = ws + off; off += (size_t)BSZ * HSZ; }
    for (int i = 0; i < 2; ++i) { p.s0l[i] = ws + off; off += (size_t)BSZ * HSZ; }
    for (int i = 0; i < 2; ++i) { p.s1h[i] = ws + off; off += (size_t)BSZ * HSZ; }
    for (int i = 0; i < 2; ++i) { p.s1l[i] = ws + off; off += (size_t)BSZ * HSZ; }
    p.accT  = (float*)(ws + off);    off += (size_t)LSEQ * BSZ * 2;
    p.bar   = (unsigned*)(ws + off); off += 8 * 64 * 2;
    p.claim = (unsigned*)(ws + off);
    p.out   = (float*)d_out;

    init_k<<<dim3(1024), dim3(256), 0, stream>>>(p);

    void* args[] = { &p };
    hipLaunchCooperativeKernel((const void*)rnn_kernel, dim3(NB), dim3(NT), args, 0, stream);
}

// Round 8
// 7252.573 us; speedup vs baseline: 5.9989x; 1.0335x over previous
//
#include <hip/hip_runtime.h>
#include <hip/hip_cooperative_groups.h>
#include <math.h>

namespace cg = cooperative_groups;

#define NB   256      // persistent blocks (1 per CU)
#define NT   256      // threads per block (4 waves)
#define BSZ  512      // batch
#define HSZ  512      // hidden
#define LSEQ 256      // sequence length
#define G3H  1536

typedef __attribute__((ext_vector_type(8))) short sh8;   // 8 bf16 = one MFMA frag
typedef __attribute__((ext_vector_type(4))) float f4;    // MFMA acc

#define MFMA(a,b,c) __builtin_amdgcn_mfma_f32_16x16x32_bf16((a),(b),(c),0,0,0)
#define AGENT __HIP_MEMORY_SCOPE_AGENT
#define WGRP  __HIP_MEMORY_SCOPE_WORKGROUP
#define RLX   __ATOMIC_RELAXED

__device__ __forceinline__ float bf2f(unsigned short u) {
    union { unsigned int i; float f; } v; v.i = ((unsigned int)u) << 16; return v.f;
}
__device__ __forceinline__ unsigned short f2bf(float f) {
    union { float f; unsigned int i; } v; v.f = f;
    unsigned int r = v.i + 0x7fffu + ((v.i >> 16) & 1u);   // RNE
    return (unsigned short)(r >> 16);
}
__device__ __forceinline__ float sigm(float v) { return 1.f / (1.f + __expf(-v)); }
__device__ __forceinline__ float tanh_(float v) { return 1.f - 2.f / (1.f + __expf(2.f * v)); }

__device__ __forceinline__ int xcc_id() {
    int x;
    asm volatile("s_getreg_b32 %0, hwreg(HW_REG_XCC_ID)" : "=s"(x));
    return x & 7;
}

// Poll via a REAL atomic RMW (inline asm: cannot be InstCombine'd into a load;
// HW atomics always execute at the XCD L2, never served by L1). sc0 = return old.
__device__ __forceinline__ unsigned poll_rmw(unsigned* p) {
    unsigned old, zero = 0;
    asm volatile("global_atomic_add %0, %1, %2, off sc0\n\ts_waitcnt vmcnt(0)"
                 : "=v"(old) : "v"(p), "v"(zero) : "memory");
    return old;
}

struct P {
    const float *z1, *y, *x, *h1;
    const float *w_ih1, *w_hh1, *b_ih1, *b_hh1;
    const float *w_ih2, *w_hh2, *b_ih2, *b_hh2;
    const float *w_fc, *b_fc;
    unsigned short *wb1, *wb2, *wbI;        // bf16 weights [1536][512]
    unsigned short *giy;                     // bf16 [512][1536]
    unsigned short *s0h[2], *s0l[2];         // bf16 hi/lo state ping-pong [512][512]
    unsigned short *s1h[2], *s1l[2];
    float *accT;                             // [256][512]
    unsigned *bar;                           // 8 group counters, 256B apart
    unsigned *claim;                         // 8 per-XCD slot counters
    float *out;                              // [512][256]
};

// ---------------- init kernel (kernel-boundary flush publishes all of this) ------
__global__ __launch_bounds__(256) void init_k(P p)
{
    int gt = blockIdx.x * 256 + threadIdx.x;
    int stride = gridDim.x * 256;
    for (int i = gt; i < G3H * HSZ; i += stride) {
        p.wb1[i] = f2bf(p.w_hh1[i]);
        p.wb2[i] = f2bf(p.w_hh2[i]);
        p.wbI[i] = f2bf(p.w_ih2[i]);
    }
    for (int i = gt; i < BSZ * HSZ; i += stride) {
        int b = i >> 9, hh = i & 511;
        float v0 = (hh < 385) ? p.z1[b * 385 + hh] : p.y[b * 127 + (hh - 385)];
        unsigned short u = f2bf(v0);
        p.s0h[0][i] = u; p.s0l[0][i] = f2bf(v0 - bf2f(u));
        float v1 = p.h1[i];
        u = f2bf(v1);
        p.s1h[0][i] = u; p.s1l[0][i] = f2bf(v1 - bf2f(u));
    }
    for (int i = gt; i < LSEQ * BSZ; i += stride) p.accT[i] = 0.f;
    for (int i = gt; i < 8 * 64; i += stride) p.bar[i] = 0u;
    for (int i = gt; i < 8; i += stride) p.claim[i] = 0u;
    for (int i = gt; i < BSZ * G3H; i += stride) {
        int b = i / G3H, j = i - b * G3H;
        float a = p.b_ih1[j];
        const float* yr = p.y + b * 127;
        const float* wr = p.w_ih1 + j * 128 + 1;
        #pragma unroll 4
        for (int k = 0; k < 127; ++k) a += yr[k] * wr[k];
        p.giy[i] = f2bf(a);
    }
}

// group barrier. fast: XCD-local group -> arrive is a WG-scope RMW (+1, not
// idempotent -> stays an atomic; no sc1 -> executes at the XCD L2); poll is an
// inline-asm atomic RMW (add 0, return old) at the same L2 line -> can never
// read stale L1. Exit invalidates L1 only (proven in R4).
// slow: R2's proven agent release/acquire (full cache maintenance).
__device__ __forceinline__ void gbar(unsigned* cnt, unsigned tgt, bool fast)
{
    __syncthreads();   // all waves drain vmcnt(0): stores committed in XCD L2
    if (threadIdx.x == 0) {
        if (fast) {
            __hip_atomic_fetch_add(cnt, 1u, RLX, WGRP);   // arrive: L2 RMW
            long guard = 0;
            while (poll_rmw(cnt) < tgt) {                 // poll: L2 RMW
                __builtin_amdgcn_s_sleep(2);
                if (++guard > (1L << 27)) break;          // anti-hang watchdog
            }
        } else {
            __hip_atomic_fetch_add(cnt, 1u, __ATOMIC_RELEASE, AGENT);
            while (__hip_atomic_load(cnt, RLX, AGENT) < tgt)
                __builtin_amdgcn_s_sleep(1);
            __builtin_amdgcn_fence(__ATOMIC_ACQUIRE, "agent");
        }
    }
    __syncthreads();
    if (fast) {
        // invalidate this CU's L1 so post-barrier loads see the group's L2 data
        asm volatile("buffer_inv sc0\n\ts_waitcnt vmcnt(0)" ::: "memory");
    }
}

__global__ __launch_bounds__(NT, 1) void rnn_kernel(P p)
{
    __shared__ __align__(16) unsigned short Wlds[3][16][520];  // phase-A weights
    __shared__ int s_xcd, s_slot;

    cg::grid_group grid = cg::this_grid();
    const int tid  = threadIdx.x;
    const int bid  = blockIdx.x;

    // ---- runtime XCD-local group formation ----
    if (tid == 0) {
        int x = xcc_id();
        s_xcd = x;
        s_slot = (int)__hip_atomic_fetch_add(&p.claim[x], 1u, RLX, AGENT);
    }
    grid.sync();   // one-time full-coherence rendezvous (claims all visible)

    bool fast = true;
    #pragma unroll
    for (int x = 0; x < 8; ++x)
        fast = fast && (__hip_atomic_load(&p.claim[x], RLX, AGENT) == 32u);

    const int by = fast ? s_xcd  : (bid >> 5);   // batch group (8)
    const int hx = fast ? s_slot : (bid & 31);   // h tile within group (32)

    const int lane = tid & 63, w = tid >> 6;
    const int m = lane & 15, quad = lane >> 4;
    const int h0 = hx * 16, b0 = by * 64 + w * 16;
    const int h  = h0 + m;
    const int bA = b0 + m;
    const int bD = b0 + quad * 4;
    unsigned* cnt = p.bar + by * 64;

    // stage phase-A weights (w_hh1 rows for this block's 16 h-cols) into LDS
    for (int c = tid; c < 3072; c += NT) {
        int row = c >> 6, ch = c & 63;
        int g = row >> 4, lc = row & 15;
        const sh8* src = (const sh8*)(p.wb1 + (size_t)(g * HSZ + h0 + lc) * HSZ) + ch;
        *(sh8*)&Wlds[g][lc][ch * 8] = *src;
    }
    __syncthreads();

    const float bfc = p.b_fc[0];
    const int hq0 = h, hq1 = HSZ + h, hq2 = 2 * HSZ + h;
    const float bh1v0 = p.b_hh1[hq0], bh1v1 = p.b_hh1[hq1], bh1v2 = p.b_hh1[hq2];
    const float bi2v0 = p.b_ih2[hq0], bi2v1 = p.b_ih2[hq1], bi2v2 = p.b_ih2[hq2];
    const float bh2v0 = p.b_hh2[hq0], bh2v1 = p.b_hh2[hq1], bh2v2 = p.b_hh2[hq2];
    const float w0c0 = p.w_ih1[(size_t)hq0 * 128];
    const float w0c1 = p.w_ih1[(size_t)hq1 * 128];
    const float w0c2 = p.w_ih1[(size_t)hq2 * 128];
    const float wfcv = p.w_fc[h];

    float gyv[4][3];
    #pragma unroll
    for (int r = 0; r < 4; ++r) {
        gyv[r][0] = bf2f(p.giy[(size_t)(bD + r) * G3H + hq0]);
        gyv[r][1] = bf2f(p.giy[(size_t)(bD + r) * G3H + hq1]);
        gyv[r][2] = bf2f(p.giy[(size_t)(bD + r) * G3H + hq2]);
    }
    // phase-B weight frag pointers (cached; L2 is never invalidated on fast path)
    const sh8* W2r = (const sh8*)p.wb2 + (size_t)hq0 * 64;
    const sh8* W2z = (const sh8*)p.wb2 + (size_t)hq1 * 64;
    const sh8* W2n = (const sh8*)p.wb2 + (size_t)hq2 * 64;
    const sh8* WIr = (const sh8*)p.wbI + (size_t)hq0 * 64;
    const sh8* WIz = (const sh8*)p.wbI + (size_t)hq1 * 64;
    const sh8* WIn = (const sh8*)p.wbI + (size_t)hq2 * 64;

    unsigned tgt = 0;

    #pragma clang loop unroll(disable)
    for (int t = 0; t < LSEQ; ++t) {
        const int pi = t & 1, po = pi ^ 1;

        // ---------- phase A: gh1 = s0 @ w_hh1^T (weights from LDS), GRU1 -> s0_new ----------
        {
            const unsigned short* sh_ = p.s0h[pi];
            const unsigned short* sl_ = p.s0l[pi];
            const sh8* Ah = (const sh8*)sh_ + (size_t)bA * 64;
            const sh8* Al = (const sh8*)sl_ + (size_t)bA * 64;
            sh8 ah[16], al[16];
            #pragma unroll
            for (int ks = 0; ks < 16; ++ks) { ah[ks] = Ah[ks * 4 + quad]; al[ks] = Al[ks * 4 + quad]; }
            f4 a0 = {0.f,0.f,0.f,0.f}, a1 = a0, a2 = a0;
            #pragma unroll
            for (int ks = 0; ks < 16; ++ks) {
                const int fo = (ks * 4 + quad) * 8;
                sh8 w_r = *(const sh8*)&Wlds[0][m][fo];
                sh8 w_z = *(const sh8*)&Wlds[1][m][fo];
                sh8 w_n = *(const sh8*)&Wlds[2][m][fo];
                a0 = MFMA(ah[ks], w_r, a0); a0 = MFMA(al[ks], w_r, a0);
                a1 = MFMA(ah[ks], w_z, a1); a1 = MFMA(al[ks], w_z, a1);
                a2 = MFMA(ah[ks], w_n, a2); a2 = MFMA(al[ks], w_n, a2);
            }
            unsigned short* oh = p.s0h[po];
            unsigned short* ol = p.s0l[po];
            #pragma unroll
            for (int r = 0; r < 4; ++r) {
                int b = bD + r;
                float o;
                if (t == 0) o = p.x[b];
                else {
                    // fast: plain load — follows gbar's buffer_inv, refills fresh from XCD L2
                    float av = fast ? p.accT[(t - 1) * BSZ + b]
                                    : __hip_atomic_load(&p.accT[(t - 1) * BSZ + b], RLX, AGENT);
                    o = fmaxf(av + bfc, 0.f);
                }
                float rr = sigm(gyv[r][0] + o * w0c0 + a0[r] + bh1v0);
                float zz = sigm(gyv[r][1] + o * w0c1 + a1[r] + bh1v1);
                float nn = tanh_(gyv[r][2] + o * w0c2 + rr * (a2[r] + bh1v2));
                size_t ix = (size_t)b * HSZ + h;
                float so = bf2f(sh_[ix]) + bf2f(sl_[ix]);
                float sn = (1.f - zz) * nn + zz * so;
                unsigned short u = f2bf(sn);
                oh[ix] = u; ol[ix] = f2bf(sn - bf2f(u));
            }
        }
        tgt += 32; gbar(cnt, tgt, fast);

        // ---------- phase B: gi2 = s0_new @ w_ih2^T, gh2 = s1 @ w_hh2^T, GRU2 + fc ------
        {
            const unsigned short* sh_ = p.s1h[pi];
            const unsigned short* sl_ = p.s1l[pi];
            const sh8* Aih = (const sh8*)p.s0h[po] + (size_t)bA * 64;
            const sh8* Ail = (const sh8*)p.s0l[po] + (size_t)bA * 64;
            const sh8* Ahh = (const sh8*)sh_ + (size_t)bA * 64;
            const sh8* Ahl = (const sh8*)sl_ + (size_t)bA * 64;

            sh8 ih[16], il[16];
            #pragma unroll
            for (int ks = 0; ks < 16; ++ks) { ih[ks] = Aih[ks * 4 + quad]; il[ks] = Ail[ks * 4 + quad]; }
            f4 ci0 = {0.f,0.f,0.f,0.f}, ci1 = ci0, ci2 = ci0;
            #pragma unroll
            for (int ks = 0; ks < 16; ++ks) {
                const int fi = ks * 4 + quad;
                sh8 wir = WIr[fi], wiz = WIz[fi], win = WIn[fi];
                ci0 = MFMA(ih[ks], wir, ci0); ci0 = MFMA(il[ks], wir, ci0);
                ci1 = MFMA(ih[ks], wiz, ci1); ci1 = MFMA(il[ks], wiz, ci1);
                ci2 = MFMA(ih[ks], win, ci2); ci2 = MFMA(il[ks], win, ci2);
            }
            sh8 hh[16], hl[16];
            #pragma unroll
            for (int ks = 0; ks < 16; ++ks) { hh[ks] = Ahh[ks * 4 + quad]; hl[ks] = Ahl[ks * 4 + quad]; }
            f4 ch0 = {0.f,0.f,0.f,0.f}, ch1 = ch0, ch2 = ch0;
            #pragma unroll
            for (int ks = 0; ks < 16; ++ks) {
                const int fi = ks * 4 + quad;
                sh8 whr = W2r[fi], whz = W2z[fi], whn = W2n[fi];
                ch0 = MFMA(hh[ks], whr, ch0); ch0 = MFMA(hl[ks], whr, ch0);
                ch1 = MFMA(hh[ks], whz, ch1); ch1 = MFMA(hl[ks], whz, ch1);
                ch2 = MFMA(hh[ks], whn, ch2); ch2 = MFMA(hl[ks], whn, ch2);
            }
            unsigned short* oh = p.s1h[po];
            unsigned short* ol = p.s1l[po];
            #pragma unroll
            for (int r = 0; r < 4; ++r) {
                int b = bD + r;
                float rr = sigm(ci0[r] + bi2v0 + ch0[r] + bh2v0);
                float zz = sigm(ci1[r] + bi2v1 + ch1[r] + bh2v1);
                float nn = tanh_(ci2[r] + bi2v2 + rr * (ch2[r] + bh2v2));
                size_t ix = (size_t)b * HSZ + h;
                float so = bf2f(sh_[ix]) + bf2f(sl_[ix]);
                float sn = (1.f - zz) * nn + zz * so;
                unsigned short u = f2bf(sn);
                oh[ix] = u; ol[ix] = f2bf(sn - bf2f(u));
                float c = sn * wfcv;
                c += __shfl_xor(c, 1); c += __shfl_xor(c, 2);
                c += __shfl_xor(c, 4); c += __shfl_xor(c, 8);
                if (m == 0) {
                    if (fast) __hip_atomic_fetch_add(&p.accT[t * BSZ + b], c, RLX, WGRP); // L2 RMW
                    else      atomicAdd(&p.accT[t * BSZ + b], c);
                }
            }
        }
        tgt += 32; gbar(cnt, tgt, fast);
    }

    // ---------- epilogue: group-local out write (follows final gbar + L1-inv) ----------
    {
        const int r = hx;
        for (int e = tid; e < 512; e += NT) {
            int idx = r * 512 + e;
            int bl = idx >> 8, t = idx & 255;
            int b = by * 64 + bl;
            float av = fast ? p.accT[t * BSZ + b]
                            : __hip_atomic_load(&p.accT[t * BSZ + b], RLX, AGENT);
            p.out[(size_t)b * 256 + t] = fmaxf(av + bfc, 0.f);
        }
    }
}

extern "C" void kernel_launch(void* const* d_in, const int* in_sizes, int n_in,
                              void* d_out, int out_size, void* d_ws, size_t ws_size,
                              hipStream_t stream)
{
    (void)in_sizes; (void)n_in; (void)out_size; (void)ws_size;
    P p;
    p.z1    = (const float*)d_in[0];
    p.y     = (const float*)d_in[1];
    p.x     = (const float*)d_in[2];
    p.h1    = (const float*)d_in[3];
    p.w_ih1 = (const float*)d_in[4];
    p.w_hh1 = (const float*)d_in[5];
    p.b_ih1 = (const float*)d_in[6];
    p.b_hh1 = (const float*)d_in[7];
    p.w_ih2 = (const float*)d_in[8];
    p.w_hh2 = (const float*)d_in[9];
    p.b_ih2 = (const float*)d_in[10];
    p.b_hh2 = (const float*)d_in[11];
    p.w_fc  = (const float*)d_in[12];
    p.b_fc  = (const float*)d_in[13];

    unsigned short* ws = (unsigned short*)d_ws;
    size_t off = 0;
    p.wb1 = ws + off; off += (size_t)G3H * HSZ;
    p.wb2 = ws + off; off += (size_t)G3H * HSZ;
    p.wbI = ws + off; off += (size_t)G3H * HSZ;
    p.giy = ws + off; off += (size_t)BSZ * G3H;
    for (int i = 0; i < 2; ++i) { p.s0h[i] = ws + off; off += (size_t)BSZ * HSZ; }
    for (int i = 0; i < 2; ++i) { p.s0l[i] = ws + off; off += (size_t)BSZ * HSZ; }
    for (int i = 0; i < 2; ++i) { p.s1h[i] = ws + off; off += (size_t)BSZ * HSZ; }
    for (int i = 0; i < 2; ++i) { p.s1l[i] = ws + off; off += (size_t)BSZ * HSZ; }
    p.accT  = (float*)(ws + off);    off += (size_t)LSEQ * BSZ * 2;
    p.bar   = (unsigned*)(ws + off); off += 8 * 64 * 2;
    p.claim = (unsigned*)(ws + off);
    p.out   = (float*)d_out;

    init_k<<<dim3(1024), dim3(256), 0, stream>>>(p);

    void* args[] = { &p };
    hipLaunchCooperativeKernel((const void*)rnn_kernel, dim3(NB), dim3(NT), args, 0, stream);
}

// Round 9
// 6095.803 us; speedup vs baseline: 7.1373x; 1.1898x over previous
//
#include <hip/hip_runtime.h>
#include <hip/hip_cooperative_groups.h>
#include <math.h>

namespace cg = cooperative_groups;

#define NB   256      // persistent blocks (1 per CU)
#define NT   256      // threads per block (4 waves)
#define BSZ  512      // batch
#define HSZ  512      // hidden
#define LSEQ 256      // sequence length
#define G3H  1536

typedef __attribute__((ext_vector_type(8))) short sh8;   // 8 bf16 = one MFMA frag
typedef __attribute__((ext_vector_type(4))) float f4;    // MFMA acc

#define MFMA(a,b,c) __builtin_amdgcn_mfma_f32_16x16x32_bf16((a),(b),(c),0,0,0)
#define AGENT __HIP_MEMORY_SCOPE_AGENT
#define WGRP  __HIP_MEMORY_SCOPE_WORKGROUP
#define RLX   __ATOMIC_RELAXED

__device__ __forceinline__ float bf2f(unsigned short u) {
    union { unsigned int i; float f; } v; v.i = ((unsigned int)u) << 16; return v.f;
}
__device__ __forceinline__ unsigned short f2bf(float f) {
    union { float f; unsigned int i; } v; v.f = f;
    unsigned int r = v.i + 0x7fffu + ((v.i >> 16) & 1u);   // RNE
    return (unsigned short)(r >> 16);
}
__device__ __forceinline__ float sigm(float v) { return 1.f / (1.f + __expf(-v)); }
__device__ __forceinline__ float tanh_(float v) { return 1.f - 2.f / (1.f + __expf(2.f * v)); }

__device__ __forceinline__ int xcc_id() {
    int x;
    asm volatile("s_getreg_b32 %0, hwreg(HW_REG_XCC_ID)" : "=s"(x));
    return x & 7;
}

// Poll via a REAL atomic RMW (proven in R7: cannot be InstCombine'd into a load;
// HW atomics always execute at the XCD L2, never served stale by L1).
__device__ __forceinline__ unsigned poll_rmw(unsigned* p) {
    unsigned old, zero = 0;
    asm volatile("global_atomic_add %0, %1, %2, off sc0\n\ts_waitcnt vmcnt(0)"
                 : "=v"(old) : "v"(p), "v"(zero) : "memory");
    return old;
}

struct P {
    const float *z1, *y, *x, *h1;
    const float *w_ih1, *w_hh1, *b_ih1, *b_hh1;
    const float *w_ih2, *w_hh2, *b_ih2, *b_hh2;
    const float *w_fc, *b_fc;
    unsigned short *wb1, *wb2, *wbI;        // bf16 weights [1536][512]
    unsigned short *giy;                     // bf16 [512][1536]
    unsigned short *s0h[2], *s0l[2];         // bf16 hi/lo state ping-pong [512][512]
    unsigned short *s1h[2], *s1l[2];
    float *accT;                             // [256][512]
    unsigned *bar;                           // 8 groups x 512 u32 barrier region
    unsigned *claim;                         // 8 per-XCD slot counters
    float *out;                              // [512][256]
};

// ---------------- init kernel (kernel-boundary flush publishes all of this) ------
__global__ __launch_bounds__(256) void init_k(P p)
{
    int gt = blockIdx.x * 256 + threadIdx.x;
    int stride = gridDim.x * 256;
    for (int i = gt; i < G3H * HSZ; i += stride) {
        p.wb1[i] = f2bf(p.w_hh1[i]);
        p.wb2[i] = f2bf(p.w_hh2[i]);
        p.wbI[i] = f2bf(p.w_ih2[i]);
    }
    for (int i = gt; i < BSZ * HSZ; i += stride) {
        int b = i >> 9, hh = i & 511;
        float v0 = (hh < 385) ? p.z1[b * 385 + hh] : p.y[b * 127 + (hh - 385)];
        unsigned short u = f2bf(v0);
        p.s0h[0][i] = u; p.s0l[0][i] = f2bf(v0 - bf2f(u));
        float v1 = p.h1[i];
        u = f2bf(v1);
        p.s1h[0][i] = u; p.s1l[0][i] = f2bf(v1 - bf2f(u));
    }
    for (int i = gt; i < LSEQ * BSZ; i += stride) p.accT[i] = 0.f;
    for (int i = gt; i < 8 * 512; i += stride) p.bar[i] = 0u;
    for (int i = gt; i < 8; i += stride) p.claim[i] = 0u;
    for (int i = gt; i < BSZ * G3H; i += stride) {
        int b = i / G3H, j = i - b * G3H;
        float a = p.b_ih1[j];
        const float* yr = p.y + b * 127;
        const float* wr = p.w_ih1 + j * 128 + 1;
        #pragma unroll 4
        for (int k = 0; k < 127; ++k) a += yr[k] * wr[k];
        p.giy[i] = f2bf(a);
    }
}

// Hierarchical fast barrier: arrive on 8 sub-lines (4 serial RMWs each);
// slot-0 combines and bumps an epoch flag; others poll the flag with backoff.
// All polls are proven atomic-RMW polls. Slow path: R2's release/acquire.
__device__ __forceinline__ void gbar(unsigned* gb, int hx, unsigned bno, bool fast)
{
    __syncthreads();   // all waves drain vmcnt(0): stores committed in XCD L2
    if (threadIdx.x == 0) {
        if (fast) {
            unsigned* sub  = gb + (hx & 7) * 32;    // 128B-spaced sub-lines
            unsigned* flag = gb + 256;
            __hip_atomic_fetch_add(sub, 1u, RLX, WGRP);
            if (hx == 0) {
                // combine: each sub-line gets 4 arrivals per barrier
                #pragma unroll
                for (int i = 0; i < 8; ++i) {
                    long g = 0;
                    while (poll_rmw(gb + i * 32) < 4u * bno) {
                        __builtin_amdgcn_s_sleep(1);
                        if (++g > (1L << 27)) break;
                    }
                }
                __hip_atomic_fetch_add(flag, 1u, RLX, WGRP);   // epoch publish
            } else {
                long g = 0;
                while (poll_rmw(flag) < bno) {
                    __builtin_amdgcn_s_sleep(4);               // backoff
                    if (++g > (1L << 27)) break;
                }
            }
        } else {
            __hip_atomic_fetch_add(gb, 1u, __ATOMIC_RELEASE, AGENT);
            while (__hip_atomic_load(gb, RLX, AGENT) < 32u * bno)
                __builtin_amdgcn_s_sleep(1);
            __builtin_amdgcn_fence(__ATOMIC_ACQUIRE, "agent");
        }
    }
    __syncthreads();
    if (fast) {
        // invalidate this CU's L1 so post-barrier loads see the group's L2 data
        asm volatile("buffer_inv sc0\n\ts_waitcnt vmcnt(0)" ::: "memory");
    }
}

__global__ __launch_bounds__(NT, 1) void rnn_kernel(P p)
{
    // ALL 9 weight matrices for this block's 16 h-cols live in LDS (146 KB):
    // 0-2: w_hh1 r/z/n   3-5: w_ih2 r/z/n   6-8: w_hh2 r/z/n
    __shared__ __align__(16) unsigned short W[9][16][520];
    __shared__ int s_xcd, s_slot;

    cg::grid_group grid = cg::this_grid();
    const int tid  = threadIdx.x;
    const int bid  = blockIdx.x;

    // ---- runtime XCD-local group formation ----
    if (tid == 0) {
        int x = xcc_id();
        s_xcd = x;
        s_slot = (int)__hip_atomic_fetch_add(&p.claim[x], 1u, RLX, AGENT);
    }
    grid.sync();   // one-time full-coherence rendezvous (claims all visible)

    bool fast = true;
    #pragma unroll
    for (int x = 0; x < 8; ++x)
        fast = fast && (__hip_atomic_load(&p.claim[x], RLX, AGENT) == 32u);

    const int by = fast ? s_xcd  : (bid >> 5);   // batch group (8)
    const int hx = fast ? s_slot : (bid & 31);   // h tile within group (32)

    const int lane = tid & 63, w = tid >> 6;
    const int m = lane & 15, quad = lane >> 4;
    const int h0 = hx * 16, b0 = by * 64 + w * 16;
    const int h  = h0 + m;
    const int bA = b0 + m;
    const int bD = b0 + quad * 4;
    unsigned* gb = p.bar + by * 512;

    // stage all 9 weight matrices into LDS
    for (int c = tid; c < 9 * 1024; c += NT) {
        int mat = c >> 10, rem = c & 1023;
        int lc = rem >> 6, ch = rem & 63;
        const unsigned short* base =
            (mat < 3) ? (p.wb1 + (size_t)(mat * HSZ + h0 + lc) * HSZ)
          : (mat < 6) ? (p.wbI + (size_t)((mat - 3) * HSZ + h0 + lc) * HSZ)
                      : (p.wb2 + (size_t)((mat - 6) * HSZ + h0 + lc) * HSZ);
        *(sh8*)&W[mat][lc][ch * 8] = *((const sh8*)base + ch);
    }
    __syncthreads();

    const float bfc = p.b_fc[0];
    const int hq0 = h, hq1 = HSZ + h, hq2 = 2 * HSZ + h;
    const float bh1v0 = p.b_hh1[hq0], bh1v1 = p.b_hh1[hq1], bh1v2 = p.b_hh1[hq2];
    const float bi2v0 = p.b_ih2[hq0], bi2v1 = p.b_ih2[hq1], bi2v2 = p.b_ih2[hq2];
    const float bh2v0 = p.b_hh2[hq0], bh2v1 = p.b_hh2[hq1], bh2v2 = p.b_hh2[hq2];
    const float w0c0 = p.w_ih1[(size_t)hq0 * 128];
    const float w0c1 = p.w_ih1[(size_t)hq1 * 128];
    const float w0c2 = p.w_ih1[(size_t)hq2 * 128];
    const float wfcv = p.w_fc[h];

    float gyv[4][3];
    #pragma unroll
    for (int r = 0; r < 4; ++r) {
        gyv[r][0] = bf2f(p.giy[(size_t)(bD + r) * G3H + hq0]);
        gyv[r][1] = bf2f(p.giy[(size_t)(bD + r) * G3H + hq1]);
        gyv[r][2] = bf2f(p.giy[(size_t)(bD + r) * G3H + hq2]);
    }

    unsigned bno = 0;

    #pragma clang loop unroll(disable)
    for (int t = 0; t < LSEQ; ++t) {
        const int pi = t & 1, po = pi ^ 1;

        // ---------- phase A: gh1 = s0 @ w_hh1^T (weights LDS), GRU1 -> s0_new ----------
        {
            const unsigned short* sh_ = p.s0h[pi];
            const unsigned short* sl_ = p.s0l[pi];
            const sh8* Ah = (const sh8*)sh_ + (size_t)bA * 64;
            const sh8* Al = (const sh8*)sl_ + (size_t)bA * 64;
            sh8 ah[16], al[16];
            #pragma unroll
            for (int ks = 0; ks < 16; ++ks) { ah[ks] = Ah[ks * 4 + quad]; al[ks] = Al[ks * 4 + quad]; }
            f4 a0 = {0.f,0.f,0.f,0.f}, a1 = a0, a2 = a0;
            #pragma unroll
            for (int ks = 0; ks < 16; ++ks) {
                const int fo = (ks * 4 + quad) * 8;
                sh8 w_r = *(const sh8*)&W[0][m][fo];
                sh8 w_z = *(const sh8*)&W[1][m][fo];
                sh8 w_n = *(const sh8*)&W[2][m][fo];
                a0 = MFMA(ah[ks], w_r, a0); a0 = MFMA(al[ks], w_r, a0);
                a1 = MFMA(ah[ks], w_z, a1); a1 = MFMA(al[ks], w_z, a1);
                a2 = MFMA(ah[ks], w_n, a2); a2 = MFMA(al[ks], w_n, a2);
            }
            unsigned short* oh = p.s0h[po];
            unsigned short* ol = p.s0l[po];
            #pragma unroll
            for (int r = 0; r < 4; ++r) {
                int b = bD + r;
                float o;
                if (t == 0) o = p.x[b];
                else {
                    float av = fast ? p.accT[(t - 1) * BSZ + b]
                                    : __hip_atomic_load(&p.accT[(t - 1) * BSZ + b], RLX, AGENT);
                    o = fmaxf(av + bfc, 0.f);
                }
                float rr = sigm(gyv[r][0] + o * w0c0 + a0[r] + bh1v0);
                float zz = sigm(gyv[r][1] + o * w0c1 + a1[r] + bh1v1);
                float nn = tanh_(gyv[r][2] + o * w0c2 + rr * (a2[r] + bh1v2));
                size_t ix = (size_t)b * HSZ + h;
                float so = bf2f(sh_[ix]) + bf2f(sl_[ix]);
                float sn = (1.f - zz) * nn + zz * so;
                unsigned short u = f2bf(sn);
                oh[ix] = u; ol[ix] = f2bf(sn - bf2f(u));
            }
        }
        ++bno; gbar(gb, hx, bno, fast);

        // ---------- phase B: gi2 = s0_new @ w_ih2^T, gh2 = s1 @ w_hh2^T (LDS), GRU2 + fc ----
        {
            const unsigned short* sh_ = p.s1h[pi];
            const unsigned short* sl_ = p.s1l[pi];
            const sh8* Aih = (const sh8*)p.s0h[po] + (size_t)bA * 64;
            const sh8* Ail = (const sh8*)p.s0l[po] + (size_t)bA * 64;
            const sh8* Ahh = (const sh8*)sh_ + (size_t)bA * 64;
            const sh8* Ahl = (const sh8*)sl_ + (size_t)bA * 64;

            sh8 ih[16], il[16];
            #pragma unroll
            for (int ks = 0; ks < 16; ++ks) { ih[ks] = Aih[ks * 4 + quad]; il[ks] = Ail[ks * 4 + quad]; }
            f4 ci0 = {0.f,0.f,0.f,0.f}, ci1 = ci0, ci2 = ci0;
            #pragma unroll
            for (int ks = 0; ks < 16; ++ks) {
                const int fo = (ks * 4 + quad) * 8;
                sh8 wir = *(const sh8*)&W[3][m][fo];
                sh8 wiz = *(const sh8*)&W[4][m][fo];
                sh8 win = *(const sh8*)&W[5][m][fo];
                ci0 = MFMA(ih[ks], wir, ci0); ci0 = MFMA(il[ks], wir, ci0);
                ci1 = MFMA(ih[ks], wiz, ci1); ci1 = MFMA(il[ks], wiz, ci1);
                ci2 = MFMA(ih[ks], win, ci2); ci2 = MFMA(il[ks], win, ci2);
            }
            sh8 hh[16], hl[16];
            #pragma unroll
            for (int ks = 0; ks < 16; ++ks) { hh[ks] = Ahh[ks * 4 + quad]; hl[ks] = Ahl[ks * 4 + quad]; }
            f4 ch0 = {0.f,0.f,0.f,0.f}, ch1 = ch0, ch2 = ch0;
            #pragma unroll
            for (int ks = 0; ks < 16; ++ks) {
                const int fo = (ks * 4 + quad) * 8;
                sh8 whr = *(const sh8*)&W[6][m][fo];
                sh8 whz = *(const sh8*)&W[7][m][fo];
                sh8 whn = *(const sh8*)&W[8][m][fo];
                ch0 = MFMA(hh[ks], whr, ch0); ch0 = MFMA(hl[ks], whr, ch0);
                ch1 = MFMA(hh[ks], whz, ch1); ch1 = MFMA(hl[ks], whz, ch1);
                ch2 = MFMA(hh[ks], whn, ch2); ch2 = MFMA(hl[ks], whn, ch2);
            }
            unsigned short* oh = p.s1h[po];
            unsigned short* ol = p.s1l[po];
            #pragma unroll
            for (int r = 0; r < 4; ++r) {
                int b = bD + r;
                float rr = sigm(ci0[r] + bi2v0 + ch0[r] + bh2v0);
                float zz = sigm(ci1[r] + bi2v1 + ch1[r] + bh2v1);
                float nn = tanh_(ci2[r] + bi2v2 + rr * (ch2[r] + bh2v2));
                size_t ix = (size_t)b * HSZ + h;
                float so = bf2f(sh_[ix]) + bf2f(sl_[ix]);
                float sn = (1.f - zz) * nn + zz * so;
                unsigned short u = f2bf(sn);
                oh[ix] = u; ol[ix] = f2bf(sn - bf2f(u));
                float c = sn * wfcv;
                c += __shfl_xor(c, 1); c += __shfl_xor(c, 2);
                c += __shfl_xor(c, 4); c += __shfl_xor(c, 8);
                if (m == 0) {
                    if (fast) __hip_atomic_fetch_add(&p.accT[t * BSZ + b], c, RLX, WGRP);
                    else      atomicAdd(&p.accT[t * BSZ + b], c);
                }
            }
        }
        ++bno; gbar(gb, hx, bno, fast);
    }

    // ---------- epilogue: group-local out write (follows final gbar + L1-inv) ----------
    {
        const int r = hx;
        for (int e = tid; e < 512; e += NT) {
            int idx = r * 512 + e;
            int bl = idx >> 8, t = idx & 255;
            int b = by * 64 + bl;
            float av = fast ? p.accT[t * BSZ + b]
                            : __hip_atomic_load(&p.accT[t * BSZ + b], RLX, AGENT);
            p.out[(size_t)b * 256 + t] = fmaxf(av + bfc, 0.f);
        }
    }
}

extern "C" void kernel_launch(void* const* d_in, const int* in_sizes, int n_in,
                              void* d_out, int out_size, void* d_ws, size_t ws_size,
                              hipStream_t stream)
{
    (void)in_sizes; (void)n_in; (void)out_size; (void)ws_size;
    P p;
    p.z1    = (const float*)d_in[0];
    p.y     = (const float*)d_in[1];
    p.x     = (const float*)d_in[2];
    p.h1    = (const float*)d_in[3];
    p.w_ih1 = (const float*)d_in[4];
    p.w_hh1 = (const float*)d_in[5];
    p.b_ih1 = (const float*)d_in[6];
    p.b_hh1 = (const float*)d_in[7];
    p.w_ih2 = (const float*)d_in[8];
    p.w_hh2 = (const float*)d_in[9];
    p.b_ih2 = (const float*)d_in[10];
    p.b_hh2 = (const float*)d_in[11];
    p.w_fc  = (const float*)d_in[12];
    p.b_fc  = (const float*)d_in[13];

    unsigned short* ws = (unsigned short*)d_ws;
    size_t off = 0;
    p.wb1 = ws + off; off += (size_t)G3H * HSZ;
    p.wb2 = ws + off; off += (size_t)G3H * HSZ;
    p.wbI = ws + off; off += (size_t)G3H * HSZ;
    p.giy = ws + off; off += (size_t)BSZ * G3H;
    for (int i = 0; i < 2; ++i) { p.s0h[i] = ws + off; off += (size_t)BSZ * HSZ; }
    for (int i = 0; i < 2; ++i) { p.s0l[i] = ws + off; off += (size_t)BSZ * HSZ; }
    for (int i = 0; i < 2; ++i) { p.s1h[i] = ws + off; off += (size_t)BSZ * HSZ; }
    for (int i = 0; i < 2; ++i) { p.s1l[i] = ws + off; off += (size_t)BSZ * HSZ; }
    p.accT  = (float*)(ws + off);    off += (size_t)LSEQ * BSZ * 2;
    p.bar   = (unsigned*)(ws + off); off += 8 * 512 * 2;
    p.claim = (unsigned*)(ws + off);
    p.out   = (float*)d_out;

    init_k<<<dim3(1024), dim3(256), 0, stream>>>(p);

    void* args[] = { &p };
    hipLaunchCooperativeKernel((const void*)rnn_kernel, dim3(NB), dim3(NT), args, 0, stream);
}